// Round 2
// baseline (124.246 us; speedup 1.0000x reference)
//
#include <hip/hip_runtime.h>

// PmLIF membrane recurrence, T timesteps, state in registers.
// Bit-exact vs the reference f32 op order:
//   t = x - v                      (one rounding; == -(v-0)+x )
//   h = v + inv_tau * t            (mul rounded, add rounded — NO fma fusion)
//   s = (h - v_th) > 0 ? 1 : 0
//   v = s ? 0 : h                  (v_reset = 0; h*(1-s)+0*s is exact select)
//
// Layout: x_seq and out are [T, B*N] row-major; inner axis contiguous, so
// per-timestep accesses are fully coalesced. One thread owns 4 consecutive
// sites (float4), loops over T with v in registers.

constexpr int T_STEPS = 64;

__device__ __forceinline__ void pmlif_step(float xv, float& v, float& s,
                                           float inv_tau, float v_th) {
    const float t = __fsub_rn(xv, v);
    const float h = __fadd_rn(v, __fmul_rn(inv_tau, t));
    const float u = __fsub_rn(h, v_th);
    const bool  b = u > 0.0f;
    s = b ? 1.0f : 0.0f;
    v = b ? 0.0f : h;
}

__global__ __launch_bounds__(256) void pmlif_scan_kernel(
    const float4* __restrict__ x,      // [T][n4] as float4
    float4* __restrict__ out,          // [T][n4] as float4
    const float* __restrict__ v_th_p,  // scalar
    const float* __restrict__ tau_p,   // scalar
    int n4)                            // (B*N)/4
{
    const int idx = blockIdx.x * blockDim.x + threadIdx.x;
    if (idx >= n4) return;

    const float v_th    = *v_th_p;
    const float inv_tau = __frcp_rn(*tau_p) ;  // 1.0f/tau, correctly rounded
    // NOTE: use exact division to match reference rounding:
    const float inv_tau_div = __fdiv_rn(1.0f, *tau_p);

    const float4* __restrict__ xp = x + idx;
    float4* __restrict__ op = out + idx;

    float4 v = make_float4(0.f, 0.f, 0.f, 0.f);

#pragma unroll 8
    for (int t = 0; t < T_STEPS; ++t) {
        const float4 xv = xp[(size_t)t * n4];
        float4 s;
        pmlif_step(xv.x, v.x, s.x, inv_tau_div, v_th);
        pmlif_step(xv.y, v.y, s.y, inv_tau_div, v_th);
        pmlif_step(xv.z, v.z, s.z, inv_tau_div, v_th);
        pmlif_step(xv.w, v.w, s.w, inv_tau_div, v_th);
        op[(size_t)t * n4] = s;
    }
    (void)inv_tau;
}

extern "C" void kernel_launch(void* const* d_in, const int* in_sizes, int n_in,
                              void* d_out, int out_size, void* d_ws, size_t ws_size,
                              hipStream_t stream) {
    const float* x    = (const float*)d_in[0];
    const float* v_th = (const float*)d_in[1];
    const float* tau  = (const float*)d_in[2];
    float* out = (float*)d_out;

    const int total = in_sizes[0];            // T * B * N
    const int bn    = total / T_STEPS;        // B * N (inner, contiguous)
    const int n4    = bn / 4;                 // float4 granularity

    const int block = 256;
    const int grid  = (n4 + block - 1) / block;

    pmlif_scan_kernel<<<grid, block, 0, stream>>>(
        (const float4*)x, (float4*)out, v_th, tau, n4);
}

// Round 4
// 117.130 us; speedup vs baseline: 1.0608x; 1.0608x over previous
//
#include <hip/hip_runtime.h>

// PmLIF membrane recurrence, T timesteps, state in registers.
// Bit-exact vs the reference f32 op order:
//   t = x - v                      (one rounding; == -(v-0)+x )
//   h = v + inv_tau * t            (mul rounded, add rounded — NO fma fusion)
//   s = (h - v_th) > 0 ? 1 : 0
//   v = s ? 0 : h                  (v_reset = 0; select is exact)
//
// Streaming kernel: x read once, spikes written once, zero reuse ->
// nontemporal (nt) loads and stores so neither stream allocates in cache.
// One thread owns 4 consecutive sites (16 B/lane, fully coalesced each
// timestep); unroll 16 keeps 16 independent loads in flight per wave.

constexpr int T_STEPS = 64;

typedef float f32x4 __attribute__((ext_vector_type(4)));

struct StepOut { float v; float s; };

__device__ __forceinline__ StepOut pmlif_step(float xv, float v,
                                              float inv_tau, float v_th) {
    const float t = __fsub_rn(xv, v);
    const float h = __fadd_rn(v, __fmul_rn(inv_tau, t));
    const float u = __fsub_rn(h, v_th);
    const bool  b = u > 0.0f;
    StepOut r;
    r.s = b ? 1.0f : 0.0f;
    r.v = b ? 0.0f : h;
    return r;
}

__global__ __launch_bounds__(256) void pmlif_scan_kernel(
    const f32x4* __restrict__ x,       // [T][n4]
    f32x4* __restrict__ out,           // [T][n4]
    const float* __restrict__ v_th_p,  // scalar
    const float* __restrict__ tau_p,   // scalar
    int n4)                            // (B*N)/4
{
    const int idx = blockIdx.x * blockDim.x + threadIdx.x;
    if (idx >= n4) return;

    const float v_th    = *v_th_p;
    const float inv_tau = __fdiv_rn(1.0f, *tau_p);

    const f32x4* __restrict__ xp = x + idx;
    f32x4* __restrict__ op = out + idx;

    float v0 = 0.f, v1 = 0.f, v2 = 0.f, v3 = 0.f;

#pragma unroll 16
    for (int t = 0; t < T_STEPS; ++t) {
        const f32x4 xv = __builtin_nontemporal_load(&xp[(size_t)t * n4]);
        const StepOut r0 = pmlif_step(xv.x, v0, inv_tau, v_th);
        const StepOut r1 = pmlif_step(xv.y, v1, inv_tau, v_th);
        const StepOut r2 = pmlif_step(xv.z, v2, inv_tau, v_th);
        const StepOut r3 = pmlif_step(xv.w, v3, inv_tau, v_th);
        v0 = r0.v; v1 = r1.v; v2 = r2.v; v3 = r3.v;
        f32x4 s;
        s.x = r0.s; s.y = r1.s; s.z = r2.s; s.w = r3.s;
        __builtin_nontemporal_store(s, &op[(size_t)t * n4]);
    }
}

extern "C" void kernel_launch(void* const* d_in, const int* in_sizes, int n_in,
                              void* d_out, int out_size, void* d_ws, size_t ws_size,
                              hipStream_t stream) {
    const float* x    = (const float*)d_in[0];
    const float* v_th = (const float*)d_in[1];
    const float* tau  = (const float*)d_in[2];
    float* out = (float*)d_out;

    const int total = in_sizes[0];            // T * B * N
    const int bn    = total / T_STEPS;        // B * N (inner, contiguous)
    const int n4    = bn / 4;                 // float4 granularity

    const int block = 256;
    const int grid  = (n4 + block - 1) / block;

    pmlif_scan_kernel<<<grid, block, 0, stream>>>(
        (const f32x4*)x, (f32x4*)out, v_th, tau, n4);
}

// Round 5
// 114.885 us; speedup vs baseline: 1.0815x; 1.0195x over previous
//
#include <hip/hip_runtime.h>

// PmLIF membrane recurrence, T timesteps, state in registers.
// Bit-exact vs the reference f32 op order:
//   t = x - v                      (one rounding; == -(v-0)+x )
//   h = v + inv_tau * t            (mul rounded, add rounded — NO fma fusion)
//   s = (h - v_th) > 0 ? 1 : 0
//   v = s ? 0 : h                  (v_reset = 0; select is exact)
//
// Streaming, zero-reuse -> nontemporal loads/stores.
// Software pipeline: register ring buffer of PF=8 x-tiles. Each iteration
// issues the load for t+PF BEFORE the store for t, so no vmcnt wait ever
// forces a store-queue drain (stores get PF iterations of retire slack).
// Fully unrolled so ring indices are compile-time constants (no scratch).

constexpr int T_STEPS = 64;
constexpr int PF      = 8;   // prefetch distance (ring depth)

typedef float f32x4 __attribute__((ext_vector_type(4)));

struct StepOut { float v; float s; };

__device__ __forceinline__ StepOut pmlif_step(float xv, float v,
                                              float inv_tau, float v_th) {
    const float t = __fsub_rn(xv, v);
    const float h = __fadd_rn(v, __fmul_rn(inv_tau, t));
    const float u = __fsub_rn(h, v_th);
    const bool  b = u > 0.0f;
    StepOut r;
    r.s = b ? 1.0f : 0.0f;
    r.v = b ? 0.0f : h;
    return r;
}

__global__ __launch_bounds__(256) void pmlif_scan_kernel(
    const f32x4* __restrict__ x,       // [T][n4]
    f32x4* __restrict__ out,           // [T][n4]
    const float* __restrict__ v_th_p,  // scalar
    const float* __restrict__ tau_p,   // scalar
    int n4)                            // (B*N)/4
{
    const int idx = blockIdx.x * blockDim.x + threadIdx.x;
    if (idx >= n4) return;

    const float v_th    = *v_th_p;
    const float inv_tau = __fdiv_rn(1.0f, *tau_p);

    const f32x4* __restrict__ xp = x + idx;
    f32x4* __restrict__ op = out + idx;

    f32x4 buf[PF];
#pragma unroll
    for (int t = 0; t < PF; ++t)
        buf[t] = __builtin_nontemporal_load(&xp[(size_t)t * n4]);

    float v0 = 0.f, v1 = 0.f, v2 = 0.f, v3 = 0.f;

#pragma unroll
    for (int t = 0; t < T_STEPS - PF; ++t) {
        const f32x4 xv = buf[t % PF];
        // issue the prefetch BEFORE this iteration's store
        buf[t % PF] = __builtin_nontemporal_load(&xp[(size_t)(t + PF) * n4]);

        const StepOut r0 = pmlif_step(xv.x, v0, inv_tau, v_th);
        const StepOut r1 = pmlif_step(xv.y, v1, inv_tau, v_th);
        const StepOut r2 = pmlif_step(xv.z, v2, inv_tau, v_th);
        const StepOut r3 = pmlif_step(xv.w, v3, inv_tau, v_th);
        v0 = r0.v; v1 = r1.v; v2 = r2.v; v3 = r3.v;
        f32x4 s;
        s.x = r0.s; s.y = r1.s; s.z = r2.s; s.w = r3.s;
        __builtin_nontemporal_store(s, &op[(size_t)t * n4]);
    }

#pragma unroll
    for (int t = T_STEPS - PF; t < T_STEPS; ++t) {
        const f32x4 xv = buf[t % PF];
        const StepOut r0 = pmlif_step(xv.x, v0, inv_tau, v_th);
        const StepOut r1 = pmlif_step(xv.y, v1, inv_tau, v_th);
        const StepOut r2 = pmlif_step(xv.z, v2, inv_tau, v_th);
        const StepOut r3 = pmlif_step(xv.w, v3, inv_tau, v_th);
        v0 = r0.v; v1 = r1.v; v2 = r2.v; v3 = r3.v;
        f32x4 s;
        s.x = r0.s; s.y = r1.s; s.z = r2.s; s.w = r3.s;
        __builtin_nontemporal_store(s, &op[(size_t)t * n4]);
    }
}

extern "C" void kernel_launch(void* const* d_in, const int* in_sizes, int n_in,
                              void* d_out, int out_size, void* d_ws, size_t ws_size,
                              hipStream_t stream) {
    const float* x    = (const float*)d_in[0];
    const float* v_th = (const float*)d_in[1];
    const float* tau  = (const float*)d_in[2];
    float* out = (float*)d_out;

    const int total = in_sizes[0];            // T * B * N
    const int bn    = total / T_STEPS;        // B * N (inner, contiguous)
    const int n4    = bn / 4;                 // float4 granularity

    const int block = 256;
    const int grid  = (n4 + block - 1) / block;

    pmlif_scan_kernel<<<grid, block, 0, stream>>>(
        (const f32x4*)x, (f32x4*)out, v_th, tau, n4);
}

// Round 6
// 102.226 us; speedup vs baseline: 1.2154x; 1.1238x over previous
//
#include <hip/hip_runtime.h>

// PmLIF membrane recurrence, T timesteps, state in registers.
// Bit-exact vs the reference f32 op order:
//   t = x - v                      (one rounding; == -(v-0)+x )
//   h = v + inv_tau * t            (mul rounded, add rounded — NO fma fusion)
//   s = (h - v_th) > 0 ? 1 : 0
//   v = s ? 0 : h                  (v_reset = 0; select is exact)
//
// R6: occupancy experiment. float2 per thread -> 2048 blocks = 8 blocks/CU
// (32 waves/CU), __launch_bounds__(256,8) caps VGPR at 64 so all are
// resident. Ring buffer PF=8 kept (prefetch t+8 issued before store t);
// grouped unroll (8 groups of 8) keeps ring indices static and address
// arithmetic cheap (per-group base pointers).

constexpr int T_STEPS = 64;
constexpr int PF      = 8;           // prefetch depth == inner unroll
constexpr int NGRP    = T_STEPS / PF;

typedef float f32x2 __attribute__((ext_vector_type(2)));

struct StepOut { float v; float s; };

__device__ __forceinline__ StepOut pmlif_step(float xv, float v,
                                              float inv_tau, float v_th) {
    const float t = __fsub_rn(xv, v);
    const float h = __fadd_rn(v, __fmul_rn(inv_tau, t));
    const float u = __fsub_rn(h, v_th);
    const bool  b = u > 0.0f;
    StepOut r;
    r.s = b ? 1.0f : 0.0f;
    r.v = b ? 0.0f : h;
    return r;
}

__global__ __launch_bounds__(256, 8) void pmlif_scan_kernel(
    const f32x2* __restrict__ x,       // [T][n2]
    f32x2* __restrict__ out,           // [T][n2]
    const float* __restrict__ v_th_p,  // scalar
    const float* __restrict__ tau_p,   // scalar
    int n2)                            // (B*N)/2
{
    const int idx = blockIdx.x * blockDim.x + threadIdx.x;
    if (idx >= n2) return;

    const float v_th    = *v_th_p;
    const float inv_tau = __fdiv_rn(1.0f, *tau_p);

    const f32x2* __restrict__ xp = x + idx;
    f32x2* __restrict__ op = out + idx;
    const size_t step = (size_t)n2;

    // prologue: fill the ring
    f32x2 buf[PF];
#pragma unroll
    for (int k = 0; k < PF; ++k)
        buf[k] = __builtin_nontemporal_load(&xp[(size_t)k * step]);

    float v0 = 0.f, v1 = 0.f;

    // main: groups 0..NGRP-2 prefetch the next group
    for (int g = 0; g < NGRP - 1; ++g) {
        const f32x2* __restrict__ xg = xp + (size_t)(g + 1) * PF * step;
        f32x2* __restrict__ og = op + (size_t)g * PF * step;
#pragma unroll
        for (int k = 0; k < PF; ++k) {
            const f32x2 xv = buf[k];
            buf[k] = __builtin_nontemporal_load(&xg[(size_t)k * step]);
            const StepOut r0 = pmlif_step(xv.x, v0, inv_tau, v_th);
            const StepOut r1 = pmlif_step(xv.y, v1, inv_tau, v_th);
            v0 = r0.v; v1 = r1.v;
            f32x2 s; s.x = r0.s; s.y = r1.s;
            __builtin_nontemporal_store(s, &og[(size_t)k * step]);
        }
    }

    // tail group: no prefetch
    {
        f32x2* __restrict__ og = op + (size_t)(NGRP - 1) * PF * step;
#pragma unroll
        for (int k = 0; k < PF; ++k) {
            const f32x2 xv = buf[k];
            const StepOut r0 = pmlif_step(xv.x, v0, inv_tau, v_th);
            const StepOut r1 = pmlif_step(xv.y, v1, inv_tau, v_th);
            v0 = r0.v; v1 = r1.v;
            f32x2 s; s.x = r0.s; s.y = r1.s;
            __builtin_nontemporal_store(s, &og[(size_t)k * step]);
        }
    }
}

extern "C" void kernel_launch(void* const* d_in, const int* in_sizes, int n_in,
                              void* d_out, int out_size, void* d_ws, size_t ws_size,
                              hipStream_t stream) {
    const float* x    = (const float*)d_in[0];
    const float* v_th = (const float*)d_in[1];
    const float* tau  = (const float*)d_in[2];
    float* out = (float*)d_out;

    const int total = in_sizes[0];            // T * B * N
    const int bn    = total / T_STEPS;        // B * N (inner, contiguous)
    const int n2    = bn / 2;                 // float2 granularity

    const int block = 256;
    const int grid  = (n2 + block - 1) / block;

    pmlif_scan_kernel<<<grid, block, 0, stream>>>(
        (const f32x2*)x, (f32x2*)out, v_th, tau, n2);
}